// Round 10
// baseline (329.714 us; speedup 1.0000x reference)
//
#include <hip/hip_runtime.h>
#include <stdint.h>

typedef unsigned short u16;
typedef unsigned int u32;
typedef __attribute__((ext_vector_type(8))) short bf16x8;
typedef __attribute__((ext_vector_type(4))) float f32x4;

__device__ __forceinline__ float bf2f(u16 u) {
    union { u32 i; float f; } v; v.i = ((u32)u) << 16; return v.f;
}
__device__ __forceinline__ u16 f2bf(float f) {
    union { float f; u32 i; } v; v.f = f;
    u32 x = v.i;
    u32 r = (x + 0x7FFFu + ((x >> 16) & 1u)) >> 16;  // RNE
    return (u16)r;
}

__device__ __forceinline__ void gld_lds16(const void* g, void* l) {
    __builtin_amdgcn_global_load_lds(
        (const __attribute__((address_space(1))) void*)g,
        (__attribute__((address_space(3))) void*)l, 16, 0, 0);
}

// ---------------- f32 -> bf16 row convert (vectorized) ---------------------
__global__ __launch_bounds__(256) void cvt_rows(
    const float* __restrict__ src, u16* __restrict__ dst, size_t total4) {
    size_t i = (size_t)blockIdx.x * 256 + threadIdx.x;  // one float4 per thread
    if (i >= total4) return;
    const float4 v = ((const float4*)src)[i];
    u16 o[4] = {f2bf(v.x), f2bf(v.y), f2bf(v.z), f2bf(v.w)};
    *(unsigned long long*)(dst + i * 4) = *(unsigned long long*)o;
}

// ---------------- transpose+convert: dst_bf16[c][r] = src_f32[r][c] --------
__global__ __launch_bounds__(256) void transpose_cvt(
    const float* __restrict__ src, u16* __restrict__ dst, int R, int C) {
    __shared__ float tile[32][33];
    int c0 = blockIdx.x * 32, r0 = blockIdx.y * 32;
    int tx = threadIdx.x & 31, ty = threadIdx.x >> 5;  // ty 0..7
    for (int rr = ty; rr < 32; rr += 8)
        tile[rr][tx] = src[(size_t)(r0 + rr) * C + c0 + tx];
    __syncthreads();
    for (int rr = ty; rr < 32; rr += 8)
        dst[(size_t)(c0 + rr) * R + r0 + tx] = f2bf(tile[tx][rr]);
}

// ---------------- GEMM v6: 128x256, BK=64, 8 waves, phase-split, 3-ring ----
// C[M][N] = A[M][K] * Bt[N][K]^T. MODE 0: bf16 out. MODE 1: f32 out + bias.
// The T3/T4 structure at the geometry it requires (wave = 64x64 out; per
// K-tile per wave: 32 MFMA, 16 ds_read_b128 -> 2:1 density):
//   3-deep ring (144 KB), prefetch distance 2, counted vmcnt(6) at tile
//   entry (drains tile t's 6 stage units, leaves t+1's 6 in flight);
//   vmcnt(0) only at the final tile. Stage for t+2 issued at t's ph1 top.
//   2 phases per tile (k-slice split), each {8 ds_read ; setprio ; 16 MFMA},
//   mid-tile barrier.
// Race ledger: ring[(t+2)%3] last read at tile t-1 ph2 (ds_reads drained by
//   compiler lgkm waits before t-1's MFMAs); stage W issued at t ph1 after
//   the boundary barrier -> ordered. W drained by vmcnt(6) at t+2 entry
//   before any read. W-W: previous writer was stage(t-1), drained @t-1.
// Swizzle: 16B chunk slot = chunk ^ (row&7), via pre-swizzled global source
//   (linear gld_lds dest, G21) + same XOR on read. Read pattern: 16 lanes,
//   rows r..r+15, same chunk -> slots hit 2x each = 2-way = free (m136).
template <int MODE>
__global__ __launch_bounds__(512, 1) void gemm_bt6(
    const u16* __restrict__ A, const u16* __restrict__ Bt,
    const float* __restrict__ bias, void* __restrict__ Cv,
    int M, int N, int K) {
    __shared__ u16 Asb[3][128 * 64];   // 48 KB
    __shared__ u16 Bsb[3][256 * 64];   // 96 KB
    int tid = threadIdx.x;
    int wid = tid >> 6, lane = tid & 63;
    int lr = lane & 15, lq = lane >> 4;
    int wr = wid >> 2, wc = wid & 3;          // 2m x 4n wave grid
    int n0 = blockIdx.x * 256, m0 = blockIdx.y * 128;
    int NT = K >> 6;
    f32x4 acc[4][4] = {};

    // stage units: g = u*512+tid; row = g>>3; phys chunk g&7 holds logical
    // chunk (g&7)^(row&7). A: 2 units (128 rows); B: 4 units (256 rows).
    #define ST_A6(u, t, bi)                                                  \
    do {                                                                     \
        int g = (u) * 512 + tid;                                             \
        int row = g >> 3;                                                    \
        int c = (g & 7) ^ (row & 7);                                         \
        int gm = m0 + row; if (gm >= M) gm = M - 1;                          \
        gld_lds16(A + (size_t)gm * K + ((t) << 6) + c * 8,                   \
                  &Asb[bi][g * 8]);                                          \
    } while (0)
    #define ST_B6(u, t, bi)                                                  \
    do {                                                                     \
        int g = (u) * 512 + tid;                                             \
        int row = g >> 3;                                                    \
        int c = (g & 7) ^ (row & 7);                                         \
        gld_lds16(Bt + (size_t)(n0 + row) * K + ((t) << 6) + c * 8,          \
                  &Bsb[bi][g * 8]);                                          \
    } while (0)

    // prologue: tiles 0 and 1 (6 units each, A then B = FIFO unit order)
    ST_A6(0, 0, 0); ST_A6(1, 0, 0);
    ST_B6(0, 0, 0); ST_B6(1, 0, 0); ST_B6(2, 0, 0); ST_B6(3, 0, 0);
    ST_A6(0, 1, 1); ST_A6(1, 1, 1);
    ST_B6(0, 1, 1); ST_B6(1, 1, 1); ST_B6(2, 1, 1); ST_B6(3, 1, 1);

    int bcur = 0;
    for (int t = 0; t < NT; ++t) {
        if (t + 1 < NT) asm volatile("s_waitcnt vmcnt(6)" ::: "memory");
        else            asm volatile("s_waitcnt vmcnt(0)" ::: "memory");
        asm volatile("s_barrier" ::: "memory");
        const u16* Ab = &Asb[bcur][0];
        const u16* Bb = &Bsb[bcur][0];
        if (t + 2 < NT) {
            int bst = bcur + 2; if (bst >= 3) bst -= 3;
            ST_A6(0, t + 2, bst); ST_A6(1, t + 2, bst);
            ST_B6(0, t + 2, bst); ST_B6(1, t + 2, bst);
            ST_B6(2, t + 2, bst); ST_B6(3, t + 2, bst);
        }
        #pragma unroll
        for (int ks = 0; ks < 2; ++ks) {
            bf16x8 a[4], b[4];
            #pragma unroll
            for (int mi = 0; mi < 4; ++mi) {
                int r = wr * 64 + mi * 16 + lr;
                int cs = (ks * 4 + lq) ^ (r & 7);
                a[mi] = *(const bf16x8*)&Ab[r * 64 + cs * 8];
            }
            #pragma unroll
            for (int ni = 0; ni < 4; ++ni) {
                int r = wc * 64 + ni * 16 + lr;
                int cs = (ks * 4 + lq) ^ (r & 7);
                b[ni] = *(const bf16x8*)&Bb[r * 64 + cs * 8];
            }
            __builtin_amdgcn_s_setprio(1);
            #pragma unroll
            for (int mi = 0; mi < 4; ++mi)
                #pragma unroll
                for (int ni = 0; ni < 4; ++ni)
                    acc[mi][ni] = __builtin_amdgcn_mfma_f32_16x16x32_bf16(
                        a[mi], b[ni], acc[mi][ni], 0, 0, 0);
            __builtin_amdgcn_s_setprio(0);
            if (ks == 0) asm volatile("s_barrier" ::: "memory");
        }
        bcur = bcur + 1; if (bcur == 3) bcur = 0;
    }
    #undef ST_A6
    #undef ST_B6

    // epilogue
    #pragma unroll
    for (int mi = 0; mi < 4; ++mi)
        #pragma unroll
        for (int ni = 0; ni < 4; ++ni) {
            int col = n0 + wc * 64 + ni * 16 + lr;
            float bv = (MODE == 1) ? bias[col] : 0.0f;
            #pragma unroll
            for (int r = 0; r < 4; ++r) {
                int row = m0 + wr * 64 + mi * 16 + lq * 4 + r;
                if (row < M) {
                    if (MODE == 0)
                        ((u16*)Cv)[(size_t)row * N + col] = f2bf(acc[mi][ni][r]);
                    else
                        ((float*)Cv)[(size_t)row * N + col] = acc[mi][ni][r] + bv;
                }
            }
        }
}

// ---------------- GEMM v5 (kept for GEMM2): 128^2, 3-ring, 1 barrier -------
template <int MODE>
__global__ __launch_bounds__(256, 3) void gemm_bt5(
    const u16* __restrict__ A, const u16* __restrict__ Bt,
    const float* __restrict__ bias, void* __restrict__ Cv,
    int M, int N, int K) {
    __shared__ u16 Asb[3][128 * 32];   // 24 KB
    __shared__ u16 Bsb[3][128 * 32];   // 24 KB
    int tid = threadIdx.x;
    int wid = tid >> 6, lane = tid & 63;
    int lr = lane & 15, lq = lane >> 4;
    int wr = wid >> 1, wc = wid & 1;
    int n0 = blockIdx.x * 128, m0 = blockIdx.y * 128;
    int NT = K >> 5;
    f32x4 acc[4][4] = {};

    #define ST_A(u, t, bi)                                                   \
    do {                                                                     \
        int g = (u) * 256 + tid;                                             \
        int row = g >> 2;                                                    \
        int c = (g & 3) ^ ((row >> 1) & 3);                                  \
        int gm = m0 + row; if (gm >= M) gm = M - 1;                          \
        gld_lds16(A + (size_t)gm * K + ((t) << 5) + c * 8,                   \
                  &Asb[bi][g * 8]);                                          \
    } while (0)
    #define ST_B(u, t, bi)                                                   \
    do {                                                                     \
        int g = (u) * 256 + tid;                                             \
        int row = g >> 2;                                                    \
        int c = (g & 3) ^ ((row >> 1) & 3);                                  \
        gld_lds16(Bt + (size_t)(n0 + row) * K + ((t) << 5) + c * 8,          \
                  &Bsb[bi][g * 8]);                                          \
    } while (0)

    ST_A(0, 0, 0); ST_A(1, 0, 0); ST_B(0, 0, 0); ST_B(1, 0, 0);
    ST_A(0, 1, 1); ST_A(1, 1, 1); ST_B(0, 1, 1); ST_B(1, 1, 1);

    int bcur = 0;
    for (int t = 0; t < NT; ++t) {
        if (t + 1 < NT) asm volatile("s_waitcnt vmcnt(4)" ::: "memory");
        else            asm volatile("s_waitcnt vmcnt(0)" ::: "memory");
        asm volatile("s_barrier" ::: "memory");
        const u16* Ab = &Asb[bcur][0];
        const u16* Bb = &Bsb[bcur][0];
        bf16x8 a[4], b[4];
        #pragma unroll
        for (int mi = 0; mi < 4; ++mi) {
            int r = wr * 64 + mi * 16 + lr;
            int cs = lq ^ ((r >> 1) & 3);
            a[mi] = *(const bf16x8*)&Ab[r * 32 + cs * 8];
        }
        #pragma unroll
        for (int ni = 0; ni < 4; ++ni) {
            int r = wc * 64 + ni * 16 + lr;
            int cs = lq ^ ((r >> 1) & 3);
            b[ni] = *(const bf16x8*)&Bb[r * 32 + cs * 8];
        }
        if (t + 2 < NT) {
            int bst = bcur + 2; if (bst >= 3) bst -= 3;
            ST_A(0, t + 2, bst); ST_A(1, t + 2, bst);
            ST_B(0, t + 2, bst); ST_B(1, t + 2, bst);
        }
        __builtin_amdgcn_s_setprio(1);
        #pragma unroll
        for (int mi = 0; mi < 4; ++mi)
            #pragma unroll
            for (int ni = 0; ni < 4; ++ni)
                acc[mi][ni] = __builtin_amdgcn_mfma_f32_16x16x32_bf16(
                    a[mi], b[ni], acc[mi][ni], 0, 0, 0);
        __builtin_amdgcn_s_setprio(0);
        bcur = bcur + 1; if (bcur == 3) bcur = 0;
    }
    #undef ST_A
    #undef ST_B

    #pragma unroll
    for (int mi = 0; mi < 4; ++mi)
        #pragma unroll
        for (int ni = 0; ni < 4; ++ni) {
            int col = n0 + wc * 64 + ni * 16 + lr;
            float bv = (MODE == 1) ? bias[col] : 0.0f;
            #pragma unroll
            for (int r = 0; r < 4; ++r) {
                int row = m0 + wr * 64 + mi * 16 + lq * 4 + r;
                if (row < M) {
                    if (MODE == 0)
                        ((u16*)Cv)[(size_t)row * N + col] = f2bf(acc[mi][ni][r]);
                    else
                        ((float*)Cv)[(size_t)row * N + col] = acc[mi][ni][r] + bv;
                }
            }
        }
}

// ---------------- bos row: attn_out[b*4097][:] = v[b, n=0, :] --------------
__global__ __launch_bounds__(256) void bos_copy(
    const u16* __restrict__ qkv, u16* __restrict__ attn_out) {
    int b = blockIdx.x;
    int c = blockIdx.y * 256 + threadIdx.x;  // 0..1023
    attn_out[(size_t)b * 4097 * 1024 + c] =
        qkv[(size_t)b * 4097 * 3072 + 2048 + c];
}

// P-LDS swizzle: layout [j 0..63][i 0..15][h 0..15] bf16, byte = j*512+i*32+2h,
// XOR 3 bank-bits (byte 4..6) with a (j,i)-hash. b128-safe (bits >= 4), and
// h0..7 / h8..15 16B-blocks stay contiguous (hash independent of h).
__device__ __forceinline__ int pswz(int j, int i, int h) {
    int byte = j * 512 + i * 32 + h * 2;
    int sw = ((j & 7) ^ ((j >> 3) & 7) ^ ((i >> 2) & 3)) & 7;
    return byte ^ (sw << 4);
}

// ---------------- fused windowed attention + talking-heads -----------------
// one WG (4 waves) per (x, b). q-token i of tile x: t = 1 + x*16 + i.
// window j=0 -> bos, j=1..48 -> t = 1 + (x*16 - 32 + (j-1)).
// causal mask j <= i+33  =>  j >= 49 always masked, pad to 64 with zeros.
__global__ __launch_bounds__(256) void attn_kernel(
    const u16* __restrict__ qkv, const float* __restrict__ w_th,
    u16* __restrict__ attn_out) {
    __shared__ u16 P[64 * 16 * 16];   // 32 KB, swizzled [j][i][h]
    __shared__ u16 vt[4][2048];       // 4 KB/wave: [4 dblk][32 j][16 d]
    __shared__ float wth_s[256];

    int tid = threadIdx.x;
    int wid = tid >> 6, lane = tid & 63;
    int x = blockIdx.x;                        // 0..255
    int b = blockIdx.y;                        // 0..3
    size_t base = (size_t)b * 4097 * 3072;
    int lr = lane & 15;
    int lq = lane >> 4;
    int lk8 = lq * 8;

    wth_s[tid] = w_th[tid];

    // ---- phase 1: per-head QK^T + mask + softmax -> P ----------------------
    for (int hh = 0; hh < 4; ++hh) {
        int h = wid * 4 + hh;
        const u16* qp = qkv + base + (size_t)(1 + x * 16 + lr) * 3072 + h * 64;
        bf16x8 aq0 = *(const bf16x8*)(qp + lk8);
        bf16x8 aq1 = *(const bf16x8*)(qp + 32 + lk8);
        f32x4 acc[4];
        #pragma unroll
        for (int jt = 0; jt < 4; ++jt) {
            int j = jt * 16 + lr;
            int tpos = x * 16 - 32 + (j - 1);
            int t = (j > 0 && tpos >= 0 && tpos < 4096) ? tpos + 1 : 0;
            const u16* kp = qkv + base + (size_t)t * 3072 + 1024 + h * 64;
            bf16x8 bk0 = *(const bf16x8*)(kp + lk8);
            bf16x8 bk1 = *(const bf16x8*)(kp + 32 + lk8);
            f32x4 c = {};
            c = __builtin_amdgcn_mfma_f32_16x16x32_bf16(aq0, bk0, c, 0, 0, 0);
            c = __builtin_amdgcn_mfma_f32_16x16x32_bf16(aq1, bk1, c, 0, 0, 0);
            acc[jt] = c;
        }
        // mask + softmax over j (16 lanes x 4 tiles hold the j axis)
        float m[4], s[4], p[4][4];
        #pragma unroll
        for (int r = 0; r < 4; ++r) m[r] = -3.0e38f;
        #pragma unroll
        for (int jt = 0; jt < 4; ++jt) {
            int j = jt * 16 + lr;
            int tpos = x * 16 - 32 + (j - 1);
            bool jvalid = (j == 0) || (tpos >= 0);
            #pragma unroll
            for (int r = 0; r < 4; ++r) {
                int i = lq * 4 + r;
                bool keep = jvalid && (j == 0 || j <= i + 33);
                float v = keep ? acc[jt][r] * 0.125f : -3.0e38f;
                p[jt][r] = v;
                m[r] = fmaxf(m[r], v);
            }
        }
        #pragma unroll
        for (int r = 0; r < 4; ++r) {
            float v = m[r];
            v = fmaxf(v, __shfl_xor(v, 1));
            v = fmaxf(v, __shfl_xor(v, 2));
            v = fmaxf(v, __shfl_xor(v, 4));
            v = fmaxf(v, __shfl_xor(v, 8));
            m[r] = v; s[r] = 0.0f;
        }
        #pragma unroll
        for (int jt = 0; jt < 4; ++jt)
            #pragma unroll
            for (int r = 0; r < 4; ++r) {
                float e = __expf(p[jt][r] - m[r]);
                p[jt][r] = e; s[r] += e;
            }
        #pragma unroll
        for (int r = 0; r < 4; ++r) {
            float v = s[r];
            v += __shfl_xor(v, 1); v += __shfl_xor(v, 2);
            v += __shfl_xor(v, 4); v += __shfl_xor(v, 8);
            s[r] = 1.0f / v;
        }
        #pragma unroll
        for (int jt = 0; jt < 4; ++jt) {
            int j = jt * 16 + lr;
            #pragma unroll
            for (int r = 0; r < 4; ++r) {
                int i = lq * 4 + r;
                *(u16*)((char*)P + pswz(j, i, h)) = f2bf(p[jt][r] * s[r]);
            }
        }
    }
    __syncthreads();

    // ---- phase 2: per-head head-mix (g) + PV MFMA --------------------------
    const u16* vtw = &vt[wid][0];
    int jloc = lane >> 1, dh = lane & 1;
    for (int gg = 0; gg < 4; ++gg) {
        int g = wid * 4 + gg;
        float wth[16];
        #pragma unroll
        for (int h2 = 0; h2 < 16; ++h2) wth[h2] = wth_s[g * 16 + h2];
        f32x4 oacc[4] = {};
        #pragma unroll
        for (int kk = 0; kk < 2; ++kk) {
            {
                int jg = kk * 32 + jloc;
                int tpos = x * 16 - 32 + (jg - 1);
                int t = (jg > 0 && tpos >= 0 && tpos < 4096) ? tpos + 1 : 0;
                const u16* src = qkv + base + (size_t)t * 3072 + 2048 + g * 64
                               + dh * 8;
                #pragma unroll
                for (int w = 0; w < 4; ++w)
                    gld_lds16(src + w * 16, &vt[wid][w * 512 + lane * 8]);
            }
            // mix heads -> A-frag (hides the staging latency under VALU).
            bf16x8 av;
            #pragma unroll
            for (int e = 0; e < 8; ++e) {
                int j = kk * 32 + lk8 + e;
                bf16x8 v0 = *(const bf16x8*)((const char*)P + pswz(j, lr, 0));
                bf16x8 v1 = *(const bf16x8*)((const char*)P + pswz(j, lr, 8));
                float s0 = 0.0f, s1 = 0.0f;
                #pragma unroll
                for (int h2 = 0; h2 < 8; ++h2) {
                    s0 += wth[h2]     * bf2f((u16)v0[h2]);
                    s1 += wth[h2 + 8] * bf2f((u16)v1[h2]);
                }
                av[e] = (short)f2bf(s0 + s1);
            }
            asm volatile("s_waitcnt vmcnt(0)" ::: "memory");
            // B-frags: scalar column gathers from row-major subtiles.
            #pragma unroll
            for (int dt = 0; dt < 4; ++dt) {
                bf16x8 bv;
                #pragma unroll
                for (int e = 0; e < 8; ++e)
                    bv[e] = (short)vtw[dt * 512 + (lk8 + e) * 16 + lr];
                oacc[dt] = __builtin_amdgcn_mfma_f32_16x16x32_bf16(
                    av, bv, oacc[dt], 0, 0, 0);
            }
        }
        #pragma unroll
        for (int dt = 0; dt < 4; ++dt) {
            int col = g * 64 + dt * 16 + lr;
            #pragma unroll
            for (int r = 0; r < 4; ++r) {
                int i = lq * 4 + r;
                size_t row = (size_t)b * 4097 + 1 + (size_t)x * 16 + i;
                attn_out[row * 1024 + col] = f2bf(oacc[dt][r]);
            }
        }
    }
}

// ---------------------------------------------------------------------------
extern "C" void kernel_launch(void* const* d_in, const int* in_sizes, int n_in,
                              void* d_out, int out_size, void* d_ws, size_t ws_size,
                              hipStream_t stream) {
    const float* x     = (const float*)d_in[0];  // (4,4097,1024) f32
    const float* w_qkv = (const float*)d_in[1];  // (1024,3072)  f32
    const float* w_out = (const float*)d_in[2];  // (1024,1024)  f32
    const float* b_out = (const float*)d_in[3];  // (1024,)      f32
    const float* w_th  = (const float*)d_in[4];  // (16,16)      f32
    float* out = (float*)d_out;                  // (4,4097,1024) f32

    const int M = 4 * 4097;  // 16388
    u16* qkv      = (u16*)d_ws;                       // M x 3072      bf16
    u16* wqkvT    = qkv + (size_t)M * 3072;           // 3072 x 1024   bf16
    u16* woutT    = wqkvT + (size_t)3072 * 1024;      // 1024 x 1024   bf16
    u16* xb       = woutT + (size_t)1024 * 1024;      // M x 1024      bf16
    u16* attn_out = xb;  // aliases xb: xb dead after GEMM1 (stream-ordered)

    transpose_cvt<<<dim3(96, 32), 256, 0, stream>>>(w_qkv, wqkvT, 1024, 3072);
    transpose_cvt<<<dim3(32, 32), 256, 0, stream>>>(w_out, woutT, 1024, 1024);

    size_t total4 = (size_t)M * 1024 / 4;  // 4,195,328 float4s
    cvt_rows<<<(int)((total4 + 255) / 256), 256, 0, stream>>>(x, xb, total4);

    int mt = (M + 127) / 128;  // 129
    gemm_bt6<0><<<dim3(3072 / 256, mt), 512, 0, stream>>>(
        xb, wqkvT, nullptr, qkv, M, 3072, 1024);

    bos_copy<<<dim3(4, 4), 256, 0, stream>>>(qkv, attn_out);
    attn_kernel<<<dim3(256, 4), 256, 0, stream>>>(qkv, w_th, attn_out);

    gemm_bt5<1><<<dim3(1024 / 128, mt), 256, 0, stream>>>(
        attn_out, woutT, b_out, out, M, 1024, 1024);
}

// Round 11
// 286.804 us; speedup vs baseline: 1.1496x; 1.1496x over previous
//
#include <hip/hip_runtime.h>
#include <stdint.h>

typedef unsigned short u16;
typedef unsigned int u32;
typedef __attribute__((ext_vector_type(8))) short bf16x8;
typedef __attribute__((ext_vector_type(4))) float f32x4;

__device__ __forceinline__ float bf2f(u16 u) {
    union { u32 i; float f; } v; v.i = ((u32)u) << 16; return v.f;
}
__device__ __forceinline__ u16 f2bf(float f) {
    union { float f; u32 i; } v; v.f = f;
    u32 x = v.i;
    u32 r = (x + 0x7FFFu + ((x >> 16) & 1u)) >> 16;  // RNE
    return (u16)r;
}

__device__ __forceinline__ void gld_lds16(const void* g, void* l) {
    __builtin_amdgcn_global_load_lds(
        (const __attribute__((address_space(1))) void*)g,
        (__attribute__((address_space(3))) void*)l, 16, 0, 0);
}

// ---------------- f32 -> bf16 row convert (vectorized) ---------------------
__global__ __launch_bounds__(256) void cvt_rows(
    const float* __restrict__ src, u16* __restrict__ dst, size_t total4) {
    size_t i = (size_t)blockIdx.x * 256 + threadIdx.x;  // one float4 per thread
    if (i >= total4) return;
    const float4 v = ((const float4*)src)[i];
    u16 o[4] = {f2bf(v.x), f2bf(v.y), f2bf(v.z), f2bf(v.w)};
    *(unsigned long long*)(dst + i * 4) = *(unsigned long long*)o;
}

// ---------------- transpose+convert: dst_bf16[c][r] = src_f32[r][c] --------
__global__ __launch_bounds__(256) void transpose_cvt(
    const float* __restrict__ src, u16* __restrict__ dst, int R, int C) {
    __shared__ float tile[32][33];
    int c0 = blockIdx.x * 32, r0 = blockIdx.y * 32;
    int tx = threadIdx.x & 31, ty = threadIdx.x >> 5;  // ty 0..7
    for (int rr = ty; rr < 32; rr += 8)
        tile[rr][tx] = src[(size_t)(r0 + rr) * C + c0 + tx];
    __syncthreads();
    for (int rr = ty; rr < 32; rr += 8)
        dst[(size_t)(c0 + rr) * R + r0 + tx] = f2bf(tile[tx][rr]);
}

// ---------------- GEMM v5 (best known: r8/r9, ~735 TF): 128^2, 3-ring ------
// C[M][N] = A[M][K] * Bt[N][K]^T. MODE 0: bf16 out. MODE 1: f32 out + bias.
// 48 KB LDS -> 3 blocks/CU (implicit cross-block overlap, m114); depth-2
// prefetch, counted vmcnt(4) mid-loop, vmcnt(0) only at last tile; single
// barrier per K-tile (3-ring removes the write hazard). Chunk swizzle
// (bank-conflict 0 measured @r8): slot = chunk ^ ((row>>1)&3) via
// pre-swizzled global source (linear gld_lds dest, G21) + same XOR on read.
// Grid: blockIdx.x = n-tile (fastest) -> A m-panel L2 reuse.
template <int MODE>
__global__ __launch_bounds__(256, 3) void gemm_bt5(
    const u16* __restrict__ A, const u16* __restrict__ Bt,
    const float* __restrict__ bias, void* __restrict__ Cv,
    int M, int N, int K) {
    __shared__ u16 Asb[3][128 * 32];   // 24 KB
    __shared__ u16 Bsb[3][128 * 32];   // 24 KB
    int tid = threadIdx.x;
    int wid = tid >> 6, lane = tid & 63;
    int lr = lane & 15, lq = lane >> 4;
    int wr = wid >> 1, wc = wid & 1;
    int n0 = blockIdx.x * 128, m0 = blockIdx.y * 128;
    int NT = K >> 5;
    f32x4 acc[4][4] = {};

    #define ST_A(u, t, bi)                                                   \
    do {                                                                     \
        int g = (u) * 256 + tid;                                             \
        int row = g >> 2;                                                    \
        int c = (g & 3) ^ ((row >> 1) & 3);                                  \
        int gm = m0 + row; if (gm >= M) gm = M - 1;                          \
        gld_lds16(A + (size_t)gm * K + ((t) << 5) + c * 8,                   \
                  &Asb[bi][g * 8]);                                          \
    } while (0)
    #define ST_B(u, t, bi)                                                   \
    do {                                                                     \
        int g = (u) * 256 + tid;                                             \
        int row = g >> 2;                                                    \
        int c = (g & 3) ^ ((row >> 1) & 3);                                  \
        gld_lds16(Bt + (size_t)(n0 + row) * K + ((t) << 5) + c * 8,          \
                  &Bsb[bi][g * 8]);                                          \
    } while (0)

    ST_A(0, 0, 0); ST_A(1, 0, 0); ST_B(0, 0, 0); ST_B(1, 0, 0);
    ST_A(0, 1, 1); ST_A(1, 1, 1); ST_B(0, 1, 1); ST_B(1, 1, 1);

    int bcur = 0;
    for (int t = 0; t < NT; ++t) {
        if (t + 1 < NT) asm volatile("s_waitcnt vmcnt(4)" ::: "memory");
        else            asm volatile("s_waitcnt vmcnt(0)" ::: "memory");
        asm volatile("s_barrier" ::: "memory");
        const u16* Ab = &Asb[bcur][0];
        const u16* Bb = &Bsb[bcur][0];
        bf16x8 a[4], b[4];
        #pragma unroll
        for (int mi = 0; mi < 4; ++mi) {
            int r = wr * 64 + mi * 16 + lr;
            int cs = lq ^ ((r >> 1) & 3);
            a[mi] = *(const bf16x8*)&Ab[r * 32 + cs * 8];
        }
        #pragma unroll
        for (int ni = 0; ni < 4; ++ni) {
            int r = wc * 64 + ni * 16 + lr;
            int cs = lq ^ ((r >> 1) & 3);
            b[ni] = *(const bf16x8*)&Bb[r * 32 + cs * 8];
        }
        if (t + 2 < NT) {
            int bst = bcur + 2; if (bst >= 3) bst -= 3;
            ST_A(0, t + 2, bst); ST_A(1, t + 2, bst);
            ST_B(0, t + 2, bst); ST_B(1, t + 2, bst);
        }
        __builtin_amdgcn_s_setprio(1);
        #pragma unroll
        for (int mi = 0; mi < 4; ++mi)
            #pragma unroll
            for (int ni = 0; ni < 4; ++ni)
                acc[mi][ni] = __builtin_amdgcn_mfma_f32_16x16x32_bf16(
                    a[mi], b[ni], acc[mi][ni], 0, 0, 0);
        __builtin_amdgcn_s_setprio(0);
        bcur = bcur + 1; if (bcur == 3) bcur = 0;
    }
    #undef ST_A
    #undef ST_B

    #pragma unroll
    for (int mi = 0; mi < 4; ++mi)
        #pragma unroll
        for (int ni = 0; ni < 4; ++ni) {
            int col = n0 + wc * 64 + ni * 16 + lr;
            float bv = (MODE == 1) ? bias[col] : 0.0f;
            #pragma unroll
            for (int r = 0; r < 4; ++r) {
                int row = m0 + wr * 64 + mi * 16 + lq * 4 + r;
                if (row < M) {
                    if (MODE == 0)
                        ((u16*)Cv)[(size_t)row * N + col] = f2bf(acc[mi][ni][r]);
                    else
                        ((float*)Cv)[(size_t)row * N + col] = acc[mi][ni][r] + bv;
                }
            }
        }
}

// ---------------- bos row: attn_out[b*4097][:] = v[b, n=0, :] --------------
__global__ __launch_bounds__(256) void bos_copy(
    const u16* __restrict__ qkv, u16* __restrict__ attn_out) {
    int b = blockIdx.x;
    int c = blockIdx.y * 256 + threadIdx.x;  // 0..1023
    attn_out[(size_t)b * 4097 * 1024 + c] =
        qkv[(size_t)b * 4097 * 3072 + 2048 + c];
}

// P-LDS swizzle: layout [j 0..63][i 0..15][h 0..15] bf16, byte = j*512+i*32+2h,
// XOR 3 bank-bits (byte 4..6) with a (j,i)-hash. b128-safe (bits >= 4), and
// h0..7 / h8..15 16B-blocks stay contiguous (hash independent of h).
__device__ __forceinline__ int pswz(int j, int i, int h) {
    int byte = j * 512 + i * 32 + h * 2;
    int sw = ((j & 7) ^ ((j >> 3) & 7) ^ ((i >> 2) & 3)) & 7;
    return byte ^ (sw << 4);
}

// ---------------- fused windowed attention + talking-heads -----------------
// one WG (4 waves) per (x, b). q-token i of tile x: t = 1 + x*16 + i.
// window j=0 -> bos, j=1..48 -> t = 1 + (x*16 - 32 + (j-1)).
// causal mask j <= i+33  =>  j >= 49 always masked, pad to 64 with zeros.
// Talking-heads mix is ONE MFMA pass (16x16x32, K zero-padded past 16):
//   out[(j,i)][g] = sum_h P[(j,i)][h] * w_th[g][h]
// done in place in P (wave wid owns j-tiles [wid*16, wid*16+16) exclusively
// for both the A-frag reads and the D writes; barriers on both sides).
__global__ __launch_bounds__(256) void attn_kernel(
    const u16* __restrict__ qkv, const float* __restrict__ w_th,
    u16* __restrict__ attn_out) {
    __shared__ u16 P[64 * 16 * 16];   // 32 KB, swizzled [j][i][h->g]
    __shared__ u16 vt[4][2048];       // 4 KB/wave: [4 dblk][32 j][16 d]

    int tid = threadIdx.x;
    int wid = tid >> 6, lane = tid & 63;
    int x = blockIdx.x;                        // 0..255
    int b = blockIdx.y;                        // 0..3
    size_t base = (size_t)b * 4097 * 3072;
    int lr = lane & 15;
    int lq = lane >> 4;
    int lk8 = lq * 8;

    // B-frag for the mix MFMA: row g = lr, k = h = lk8+e (zero for k >= 16).
    bf16x8 bwth = {};
    if (lq < 2) {
        #pragma unroll
        for (int e = 0; e < 8; ++e)
            bwth[e] = (short)f2bf(w_th[lr * 16 + lk8 + e]);
    }

    // ---- phase 1: per-head QK^T + mask + softmax -> P ----------------------
    for (int hh = 0; hh < 4; ++hh) {
        int h = wid * 4 + hh;
        const u16* qp = qkv + base + (size_t)(1 + x * 16 + lr) * 3072 + h * 64;
        bf16x8 aq0 = *(const bf16x8*)(qp + lk8);
        bf16x8 aq1 = *(const bf16x8*)(qp + 32 + lk8);
        f32x4 acc[4];
        #pragma unroll
        for (int jt = 0; jt < 4; ++jt) {
            int j = jt * 16 + lr;
            int tpos = x * 16 - 32 + (j - 1);
            int t = (j > 0 && tpos >= 0 && tpos < 4096) ? tpos + 1 : 0;
            const u16* kp = qkv + base + (size_t)t * 3072 + 1024 + h * 64;
            bf16x8 bk0 = *(const bf16x8*)(kp + lk8);
            bf16x8 bk1 = *(const bf16x8*)(kp + 32 + lk8);
            f32x4 c = {};
            c = __builtin_amdgcn_mfma_f32_16x16x32_bf16(aq0, bk0, c, 0, 0, 0);
            c = __builtin_amdgcn_mfma_f32_16x16x32_bf16(aq1, bk1, c, 0, 0, 0);
            acc[jt] = c;
        }
        // mask + softmax over j (16 lanes x 4 tiles hold the j axis)
        float m[4], s[4], p[4][4];
        #pragma unroll
        for (int r = 0; r < 4; ++r) m[r] = -3.0e38f;
        #pragma unroll
        for (int jt = 0; jt < 4; ++jt) {
            int j = jt * 16 + lr;
            int tpos = x * 16 - 32 + (j - 1);
            bool jvalid = (j == 0) || (tpos >= 0);
            #pragma unroll
            for (int r = 0; r < 4; ++r) {
                int i = lq * 4 + r;
                bool keep = jvalid && (j == 0 || j <= i + 33);
                float v = keep ? acc[jt][r] * 0.125f : -3.0e38f;
                p[jt][r] = v;
                m[r] = fmaxf(m[r], v);
            }
        }
        #pragma unroll
        for (int r = 0; r < 4; ++r) {
            float v = m[r];
            v = fmaxf(v, __shfl_xor(v, 1));
            v = fmaxf(v, __shfl_xor(v, 2));
            v = fmaxf(v, __shfl_xor(v, 4));
            v = fmaxf(v, __shfl_xor(v, 8));
            m[r] = v; s[r] = 0.0f;
        }
        #pragma unroll
        for (int jt = 0; jt < 4; ++jt)
            #pragma unroll
            for (int r = 0; r < 4; ++r) {
                float e = __expf(p[jt][r] - m[r]);
                p[jt][r] = e; s[r] += e;
            }
        #pragma unroll
        for (int r = 0; r < 4; ++r) {
            float v = s[r];
            v += __shfl_xor(v, 1); v += __shfl_xor(v, 2);
            v += __shfl_xor(v, 4); v += __shfl_xor(v, 8);
            s[r] = 1.0f / v;
        }
        #pragma unroll
        for (int jt = 0; jt < 4; ++jt) {
            int j = jt * 16 + lr;
            #pragma unroll
            for (int r = 0; r < 4; ++r) {
                int i = lq * 4 + r;
                *(u16*)((char*)P + pswz(j, i, h)) = f2bf(p[jt][r] * s[r]);
            }
        }
    }
    __syncthreads();

    // ---- mix: 16 MFMA per wave, in place in P ------------------------------
    // A-frag (tile j): row i = lr, k = h = lk8+e (lq<2 reads the contiguous
    // 16B h-block; lq>=2 zero). D: col g = lr, row i = lq*4+r -> write back
    // into the h-slot (now g-slot) of the same (j,i) rows.
    #pragma unroll
    for (int jj = 0; jj < 16; ++jj) {
        int j = wid * 16 + jj;
        bf16x8 a = {};
        if (lq < 2)
            a = *(const bf16x8*)((const char*)P + pswz(j, lr, lk8));
        f32x4 c = {};
        c = __builtin_amdgcn_mfma_f32_16x16x32_bf16(a, bwth, c, 0, 0, 0);
        #pragma unroll
        for (int r = 0; r < 4; ++r)
            *(u16*)((char*)P + pswz(j, lq * 4 + r, lr)) = f2bf(c[r]);
    }
    __syncthreads();

    // ---- phase 2: per-head PV MFMA (mixed P read directly) -----------------
    const u16* vtw = &vt[wid][0];
    int jloc = lane >> 1, dh = lane & 1;
    for (int gg = 0; gg < 4; ++gg) {
        int g = wid * 4 + gg;
        f32x4 oacc[4] = {};
        #pragma unroll
        for (int kk = 0; kk < 2; ++kk) {
            {
                int jg = kk * 32 + jloc;
                int tpos = x * 16 - 32 + (jg - 1);
                int t = (jg > 0 && tpos >= 0 && tpos < 4096) ? tpos + 1 : 0;
                const u16* src = qkv + base + (size_t)t * 3072 + 2048 + g * 64
                               + dh * 8;
                #pragma unroll
                for (int w = 0; w < 4; ++w)
                    gld_lds16(src + w * 16, &vt[wid][w * 512 + lane * 8]);
            }
            // A-frag: av[e] = mixed[(j = kk*32 + lk8 + e, i = lr)][g]
            bf16x8 av;
            #pragma unroll
            for (int e = 0; e < 8; ++e)
                av[e] = (short)*(const u16*)
                    ((const char*)P + pswz(kk * 32 + lk8 + e, lr, g));
            asm volatile("s_waitcnt vmcnt(0)" ::: "memory");
            // B-frags: scalar column gathers from row-major subtiles.
            #pragma unroll
            for (int dt = 0; dt < 4; ++dt) {
                bf16x8 bv;
                #pragma unroll
                for (int e = 0; e < 8; ++e)
                    bv[e] = (short)vtw[dt * 512 + (lk8 + e) * 16 + lr];
                oacc[dt] = __builtin_amdgcn_mfma_f32_16x16x32_bf16(
                    av, bv, oacc[dt], 0, 0, 0);
            }
        }
        #pragma unroll
        for (int dt = 0; dt < 4; ++dt) {
            int col = g * 64 + dt * 16 + lr;
            #pragma unroll
            for (int r = 0; r < 4; ++r) {
                int i = lq * 4 + r;
                size_t row = (size_t)b * 4097 + 1 + (size_t)x * 16 + i;
                attn_out[row * 1024 + col] = f2bf(oacc[dt][r]);
            }
        }
    }
}

// ---------------------------------------------------------------------------
extern "C" void kernel_launch(void* const* d_in, const int* in_sizes, int n_in,
                              void* d_out, int out_size, void* d_ws, size_t ws_size,
                              hipStream_t stream) {
    const float* x     = (const float*)d_in[0];  // (4,4097,1024) f32
    const float* w_qkv = (const float*)d_in[1];  // (1024,3072)  f32
    const float* w_out = (const float*)d_in[2];  // (1024,1024)  f32
    const float* b_out = (const float*)d_in[3];  // (1024,)      f32
    const float* w_th  = (const float*)d_in[4];  // (16,16)      f32
    float* out = (float*)d_out;                  // (4,4097,1024) f32

    const int M = 4 * 4097;  // 16388
    u16* qkv      = (u16*)d_ws;                       // M x 3072      bf16
    u16* wqkvT    = qkv + (size_t)M * 3072;           // 3072 x 1024   bf16
    u16* woutT    = wqkvT + (size_t)3072 * 1024;      // 1024 x 1024   bf16
    u16* xb       = woutT + (size_t)1024 * 1024;      // M x 1024      bf16
    u16* attn_out = xb;  // aliases xb: xb dead after GEMM1 (stream-ordered)

    transpose_cvt<<<dim3(96, 32), 256, 0, stream>>>(w_qkv, wqkvT, 1024, 3072);
    transpose_cvt<<<dim3(32, 32), 256, 0, stream>>>(w_out, woutT, 1024, 1024);

    size_t total4 = (size_t)M * 1024 / 4;  // 4,195,328 float4s
    cvt_rows<<<(int)((total4 + 255) / 256), 256, 0, stream>>>(x, xb, total4);

    int mt = (M + 127) / 128;  // 129
    gemm_bt5<0><<<dim3(3072 / 128, mt), 256, 0, stream>>>(
        xb, wqkvT, nullptr, qkv, M, 3072, 1024);

    bos_copy<<<dim3(4, 4), 256, 0, stream>>>(qkv, attn_out);
    attn_kernel<<<dim3(256, 4), 256, 0, stream>>>(qkv, w_th, attn_out);

    gemm_bt5<1><<<dim3(1024 / 128, mt), 256, 0, stream>>>(
        attn_out, woutT, b_out, out, M, 1024, 1024);
}

// Round 12
// 276.735 us; speedup vs baseline: 1.1914x; 1.0364x over previous
//
#include <hip/hip_runtime.h>
#include <stdint.h>

typedef unsigned short u16;
typedef unsigned int u32;
typedef __attribute__((ext_vector_type(8))) short bf16x8;
typedef __attribute__((ext_vector_type(4))) float f32x4;

__device__ __forceinline__ float bf2f(u16 u) {
    union { u32 i; float f; } v; v.i = ((u32)u) << 16; return v.f;
}
__device__ __forceinline__ u16 f2bf(float f) {
    union { float f; u32 i; } v; v.f = f;
    u32 x = v.i;
    u32 r = (x + 0x7FFFu + ((x >> 16) & 1u)) >> 16;  // RNE
    return (u16)r;
}

__device__ __forceinline__ void gld_lds16(const void* g, void* l) {
    __builtin_amdgcn_global_load_lds(
        (const __attribute__((address_space(1))) void*)g,
        (__attribute__((address_space(3))) void*)l, 16, 0, 0);
}

// ---------------- f32 -> bf16 row convert (vectorized) ---------------------
__global__ __launch_bounds__(256) void cvt_rows(
    const float* __restrict__ src, u16* __restrict__ dst, size_t total4) {
    size_t i = (size_t)blockIdx.x * 256 + threadIdx.x;  // one float4 per thread
    if (i >= total4) return;
    const float4 v = ((const float4*)src)[i];
    u16 o[4] = {f2bf(v.x), f2bf(v.y), f2bf(v.z), f2bf(v.w)};
    *(unsigned long long*)(dst + i * 4) = *(unsigned long long*)o;
}

// ---------------- transpose+convert: dst_bf16[c][r] = src_f32[r][c] --------
__global__ __launch_bounds__(256) void transpose_cvt(
    const float* __restrict__ src, u16* __restrict__ dst, int R, int C) {
    __shared__ float tile[32][33];
    int c0 = blockIdx.x * 32, r0 = blockIdx.y * 32;
    int tx = threadIdx.x & 31, ty = threadIdx.x >> 5;  // ty 0..7
    for (int rr = ty; rr < 32; rr += 8)
        tile[rr][tx] = src[(size_t)(r0 + rr) * C + c0 + tx];
    __syncthreads();
    for (int rr = ty; rr < 32; rr += 8)
        dst[(size_t)(c0 + rr) * R + r0 + tx] = f2bf(tile[tx][rr]);
}

// ---------------- GEMM v7: r8/r9 schedule, wave tile 64x128 ----------------
// C[M][N] = A[M][K] * Bt[N][K]^T. MODE 0: bf16 out. MODE 1: f32 out + bias.
// Block 128x256, BK=32, 4 waves (2m x 2n), 3-deep LDS ring (72 KB -> 2
// blocks/CU), depth-2 prefetch, counted vmcnt(6) mid-loop (6 stage units
// per tile: 2 A + 4 B), vmcnt(0) only at last tile; single barrier per
// K-tile (3-ring removes the write hazard — same ledger as r8/r9):
//   R-W: stage(t+2)->ring[(t+2)%3], last read in iter t-1 (lgkm-drained
//        before t-1's MFMAs), stage issued after barrier(t). safe.
//   W-W: previous writer stage(t-1) drained by vmcnt at t-1. safe.
//   vmcnt: at t entry outstanding = stage(t) 6 + stage(t+1) 6; vmcnt(6)
//        drains exactly stage(t) (FIFO).
// Wave tile 64x128: 12 ds_read_b128 per 32 MFMA = 384 B/MFMA (-25% LDS
// traffic vs 64x64) + 2x MFMA cluster per barrier.
// Chunk swizzle (bank-conflict 0 measured @r8): slot = chunk ^ ((row>>1)&3)
// via pre-swizzled global source (linear gld_lds dest, G21) + same on read.
// Grid: blockIdx.x = n-tile (fastest) -> A m-panel L2 reuse.
template <int MODE>
__global__ __launch_bounds__(256, 2) void gemm_bt7(
    const u16* __restrict__ A, const u16* __restrict__ Bt,
    const float* __restrict__ bias, void* __restrict__ Cv,
    int M, int N, int K) {
    __shared__ u16 Asb[3][128 * 32];   // 24 KB
    __shared__ u16 Bsb[3][256 * 32];   // 48 KB
    int tid = threadIdx.x;
    int wid = tid >> 6, lane = tid & 63;
    int lr = lane & 15, lq = lane >> 4;
    int wr = wid >> 1, wc = wid & 1;          // 2m x 2n, wave = 64m x 128n
    int n0 = blockIdx.x * 256, m0 = blockIdx.y * 128;
    int NT = K >> 5;
    f32x4 acc[4][8] = {};

    #define ST_A(u, t, bi)                                                   \
    do {                                                                     \
        int g = (u) * 256 + tid;            /* 0..511 */                     \
        int row = g >> 2;                   /* 0..127 */                     \
        int c = (g & 3) ^ ((row >> 1) & 3);                                  \
        int gm = m0 + row; if (gm >= M) gm = M - 1;                          \
        gld_lds16(A + (size_t)gm * K + ((t) << 5) + c * 8,                   \
                  &Asb[bi][g * 8]);                                          \
    } while (0)
    #define ST_B(u, t, bi)                                                   \
    do {                                                                     \
        int g = (u) * 256 + tid;            /* 0..1023 */                    \
        int row = g >> 2;                   /* 0..255 */                     \
        int c = (g & 3) ^ ((row >> 1) & 3);                                  \
        gld_lds16(Bt + (size_t)(n0 + row) * K + ((t) << 5) + c * 8,          \
                  &Bsb[bi][g * 8]);                                          \
    } while (0)
    #define ST_TILE(t, bi)                                                   \
    do {                                                                     \
        ST_A(0, t, bi); ST_A(1, t, bi);                                      \
        ST_B(0, t, bi); ST_B(1, t, bi); ST_B(2, t, bi); ST_B(3, t, bi);      \
    } while (0)

    ST_TILE(0, 0);
    ST_TILE(1, 1);

    int bcur = 0;
    for (int t = 0; t < NT; ++t) {
        if (t + 1 < NT) asm volatile("s_waitcnt vmcnt(6)" ::: "memory");
        else            asm volatile("s_waitcnt vmcnt(0)" ::: "memory");
        asm volatile("s_barrier" ::: "memory");
        const u16* Ab = &Asb[bcur][0];
        const u16* Bb = &Bsb[bcur][0];
        bf16x8 a[4], b[8];
        #pragma unroll
        for (int mi = 0; mi < 4; ++mi) {
            int r = wr * 64 + mi * 16 + lr;
            int cs = lq ^ ((r >> 1) & 3);
            a[mi] = *(const bf16x8*)&Ab[r * 32 + cs * 8];
        }
        #pragma unroll
        for (int ni = 0; ni < 8; ++ni) {
            int r = wc * 128 + ni * 16 + lr;
            int cs = lq ^ ((r >> 1) & 3);
            b[ni] = *(const bf16x8*)&Bb[r * 32 + cs * 8];
        }
        if (t + 2 < NT) {
            int bst = bcur + 2; if (bst >= 3) bst -= 3;
            ST_TILE(t + 2, bst);
        }
        __builtin_amdgcn_s_setprio(1);
        #pragma unroll
        for (int mi = 0; mi < 4; ++mi)
            #pragma unroll
            for (int ni = 0; ni < 8; ++ni)
                acc[mi][ni] = __builtin_amdgcn_mfma_f32_16x16x32_bf16(
                    a[mi], b[ni], acc[mi][ni], 0, 0, 0);
        __builtin_amdgcn_s_setprio(0);
        bcur = bcur + 1; if (bcur == 3) bcur = 0;
    }
    #undef ST_A
    #undef ST_B
    #undef ST_TILE

    #pragma unroll
    for (int mi = 0; mi < 4; ++mi)
        #pragma unroll
        for (int ni = 0; ni < 8; ++ni) {
            int col = n0 + wc * 128 + ni * 16 + lr;
            float bv = (MODE == 1) ? bias[col] : 0.0f;
            #pragma unroll
            for (int r = 0; r < 4; ++r) {
                int row = m0 + wr * 64 + mi * 16 + lq * 4 + r;
                if (row < M) {
                    if (MODE == 0)
                        ((u16*)Cv)[(size_t)row * N + col] = f2bf(acc[mi][ni][r]);
                    else
                        ((float*)Cv)[(size_t)row * N + col] = acc[mi][ni][r] + bv;
                }
            }
        }
}

// ---------------- bos row: attn_out[b*4097][:] = v[b, n=0, :] --------------
__global__ __launch_bounds__(256) void bos_copy(
    const u16* __restrict__ qkv, u16* __restrict__ attn_out) {
    int b = blockIdx.x;
    int c = blockIdx.y * 256 + threadIdx.x;  // 0..1023
    attn_out[(size_t)b * 4097 * 1024 + c] =
        qkv[(size_t)b * 4097 * 3072 + 2048 + c];
}

// P-LDS swizzle: layout [j 0..63][i 0..15][h 0..15] bf16, byte = j*512+i*32+2h,
// XOR 3 bank-bits (byte 4..6) with a (j,i)-hash. b128-safe (bits >= 4), and
// h0..7 / h8..15 16B-blocks stay contiguous (hash independent of h).
__device__ __forceinline__ int pswz(int j, int i, int h) {
    int byte = j * 512 + i * 32 + h * 2;
    int sw = ((j & 7) ^ ((j >> 3) & 7) ^ ((i >> 2) & 3)) & 7;
    return byte ^ (sw << 4);
}

// ---------------- fused windowed attention + talking-heads -----------------
// one WG (4 waves) per (x, b). q-token i of tile x: t = 1 + x*16 + i.
// window j=0 -> bos, j=1..48 -> t = 1 + (x*16 - 32 + (j-1)).
// causal mask j <= i+33  =>  j >= 49 always masked, pad to 64 with zeros.
// Talking-heads mix: ONE MFMA pass in place in P (r11, verified).
__global__ __launch_bounds__(256) void attn_kernel(
    const u16* __restrict__ qkv, const float* __restrict__ w_th,
    u16* __restrict__ attn_out) {
    __shared__ u16 P[64 * 16 * 16];   // 32 KB, swizzled [j][i][h->g]
    __shared__ u16 vt[4][2048];       // 4 KB/wave: [4 dblk][32 j][16 d]

    int tid = threadIdx.x;
    int wid = tid >> 6, lane = tid & 63;
    int x = blockIdx.x;                        // 0..255
    int b = blockIdx.y;                        // 0..3
    size_t base = (size_t)b * 4097 * 3072;
    int lr = lane & 15;
    int lq = lane >> 4;
    int lk8 = lq * 8;

    // B-frag for the mix MFMA: row g = lr, k = h = lk8+e (zero for k >= 16).
    bf16x8 bwth = {};
    if (lq < 2) {
        #pragma unroll
        for (int e = 0; e < 8; ++e)
            bwth[e] = (short)f2bf(w_th[lr * 16 + lk8 + e]);
    }

    // ---- phase 1: per-head QK^T + mask + softmax -> P ----------------------
    for (int hh = 0; hh < 4; ++hh) {
        int h = wid * 4 + hh;
        const u16* qp = qkv + base + (size_t)(1 + x * 16 + lr) * 3072 + h * 64;
        bf16x8 aq0 = *(const bf16x8*)(qp + lk8);
        bf16x8 aq1 = *(const bf16x8*)(qp + 32 + lk8);
        f32x4 acc[4];
        #pragma unroll
        for (int jt = 0; jt < 4; ++jt) {
            int j = jt * 16 + lr;
            int tpos = x * 16 - 32 + (j - 1);
            int t = (j > 0 && tpos >= 0 && tpos < 4096) ? tpos + 1 : 0;
            const u16* kp = qkv + base + (size_t)t * 3072 + 1024 + h * 64;
            bf16x8 bk0 = *(const bf16x8*)(kp + lk8);
            bf16x8 bk1 = *(const bf16x8*)(kp + 32 + lk8);
            f32x4 c = {};
            c = __builtin_amdgcn_mfma_f32_16x16x32_bf16(aq0, bk0, c, 0, 0, 0);
            c = __builtin_amdgcn_mfma_f32_16x16x32_bf16(aq1, bk1, c, 0, 0, 0);
            acc[jt] = c;
        }
        // mask + softmax over j (16 lanes x 4 tiles hold the j axis)
        float m[4], s[4], p[4][4];
        #pragma unroll
        for (int r = 0; r < 4; ++r) m[r] = -3.0e38f;
        #pragma unroll
        for (int jt = 0; jt < 4; ++jt) {
            int j = jt * 16 + lr;
            int tpos = x * 16 - 32 + (j - 1);
            bool jvalid = (j == 0) || (tpos >= 0);
            #pragma unroll
            for (int r = 0; r < 4; ++r) {
                int i = lq * 4 + r;
                bool keep = jvalid && (j == 0 || j <= i + 33);
                float v = keep ? acc[jt][r] * 0.125f : -3.0e38f;
                p[jt][r] = v;
                m[r] = fmaxf(m[r], v);
            }
        }
        #pragma unroll
        for (int r = 0; r < 4; ++r) {
            float v = m[r];
            v = fmaxf(v, __shfl_xor(v, 1));
            v = fmaxf(v, __shfl_xor(v, 2));
            v = fmaxf(v, __shfl_xor(v, 4));
            v = fmaxf(v, __shfl_xor(v, 8));
            m[r] = v; s[r] = 0.0f;
        }
        #pragma unroll
        for (int jt = 0; jt < 4; ++jt)
            #pragma unroll
            for (int r = 0; r < 4; ++r) {
                float e = __expf(p[jt][r] - m[r]);
                p[jt][r] = e; s[r] += e;
            }
        #pragma unroll
        for (int r = 0; r < 4; ++r) {
            float v = s[r];
            v += __shfl_xor(v, 1); v += __shfl_xor(v, 2);
            v += __shfl_xor(v, 4); v += __shfl_xor(v, 8);
            s[r] = 1.0f / v;
        }
        #pragma unroll
        for (int jt = 0; jt < 4; ++jt) {
            int j = jt * 16 + lr;
            #pragma unroll
            for (int r = 0; r < 4; ++r) {
                int i = lq * 4 + r;
                *(u16*)((char*)P + pswz(j, i, h)) = f2bf(p[jt][r] * s[r]);
            }
        }
    }
    __syncthreads();

    // ---- mix: 16 MFMA per wave, in place in P ------------------------------
    #pragma unroll
    for (int jj = 0; jj < 16; ++jj) {
        int j = wid * 16 + jj;
        bf16x8 a = {};
        if (lq < 2)
            a = *(const bf16x8*)((const char*)P + pswz(j, lr, lk8));
        f32x4 c = {};
        c = __builtin_amdgcn_mfma_f32_16x16x32_bf16(a, bwth, c, 0, 0, 0);
        #pragma unroll
        for (int r = 0; r < 4; ++r)
            *(u16*)((char*)P + pswz(j, lq * 4 + r, lr)) = f2bf(c[r]);
    }
    __syncthreads();

    // ---- phase 2: per-head PV MFMA (mixed P read directly) -----------------
    const u16* vtw = &vt[wid][0];
    int jloc = lane >> 1, dh = lane & 1;
    for (int gg = 0; gg < 4; ++gg) {
        int g = wid * 4 + gg;
        f32x4 oacc[4] = {};
        #pragma unroll
        for (int kk = 0; kk < 2; ++kk) {
            {
                int jg = kk * 32 + jloc;
                int tpos = x * 16 - 32 + (jg - 1);
                int t = (jg > 0 && tpos >= 0 && tpos < 4096) ? tpos + 1 : 0;
                const u16* src = qkv + base + (size_t)t * 3072 + 2048 + g * 64
                               + dh * 8;
                #pragma unroll
                for (int w = 0; w < 4; ++w)
                    gld_lds16(src + w * 16, &vt[wid][w * 512 + lane * 8]);
            }
            // A-frag: av[e] = mixed[(j = kk*32 + lk8 + e, i = lr)][g]
            bf16x8 av;
            #pragma unroll
            for (int e = 0; e < 8; ++e)
                av[e] = (short)*(const u16*)
                    ((const char*)P + pswz(kk * 32 + lk8 + e, lr, g));
            asm volatile("s_waitcnt vmcnt(0)" ::: "memory");
            // B-frags: scalar column gathers from row-major subtiles.
            #pragma unroll
            for (int dt = 0; dt < 4; ++dt) {
                bf16x8 bv;
                #pragma unroll
                for (int e = 0; e < 8; ++e)
                    bv[e] = (short)vtw[dt * 512 + (lk8 + e) * 16 + lr];
                oacc[dt] = __builtin_amdgcn_mfma_f32_16x16x32_bf16(
                    av, bv, oacc[dt], 0, 0, 0);
            }
        }
        #pragma unroll
        for (int dt = 0; dt < 4; ++dt) {
            int col = g * 64 + dt * 16 + lr;
            #pragma unroll
            for (int r = 0; r < 4; ++r) {
                int i = lq * 4 + r;
                size_t row = (size_t)b * 4097 + 1 + (size_t)x * 16 + i;
                attn_out[row * 1024 + col] = f2bf(oacc[dt][r]);
            }
        }
    }
}

// ---------------------------------------------------------------------------
extern "C" void kernel_launch(void* const* d_in, const int* in_sizes, int n_in,
                              void* d_out, int out_size, void* d_ws, size_t ws_size,
                              hipStream_t stream) {
    const float* x     = (const float*)d_in[0];  // (4,4097,1024) f32
    const float* w_qkv = (const float*)d_in[1];  // (1024,3072)  f32
    const float* w_out = (const float*)d_in[2];  // (1024,1024)  f32
    const float* b_out = (const float*)d_in[3];  // (1024,)      f32
    const float* w_th  = (const float*)d_in[4];  // (16,16)      f32
    float* out = (float*)d_out;                  // (4,4097,1024) f32

    const int M = 4 * 4097;  // 16388
    u16* qkv      = (u16*)d_ws;                       // M x 3072      bf16
    u16* wqkvT    = qkv + (size_t)M * 3072;           // 3072 x 1024   bf16
    u16* woutT    = wqkvT + (size_t)3072 * 1024;      // 1024 x 1024   bf16
    u16* xb       = woutT + (size_t)1024 * 1024;      // M x 1024      bf16
    u16* attn_out = xb;  // aliases xb: xb dead after GEMM1 (stream-ordered)

    transpose_cvt<<<dim3(96, 32), 256, 0, stream>>>(w_qkv, wqkvT, 1024, 3072);
    transpose_cvt<<<dim3(32, 32), 256, 0, stream>>>(w_out, woutT, 1024, 1024);

    size_t total4 = (size_t)M * 1024 / 4;  // 4,195,328 float4s
    cvt_rows<<<(int)((total4 + 255) / 256), 256, 0, stream>>>(x, xb, total4);

    int mt = (M + 127) / 128;  // 129
    gemm_bt7<0><<<dim3(3072 / 256, mt), 256, 0, stream>>>(
        xb, wqkvT, nullptr, qkv, M, 3072, 1024);

    bos_copy<<<dim3(4, 4), 256, 0, stream>>>(qkv, attn_out);
    attn_kernel<<<dim3(256, 4), 256, 0, stream>>>(qkv, w_th, attn_out);

    gemm_bt7<1><<<dim3(1024 / 256, mt), 256, 0, stream>>>(
        attn_out, woutT, b_out, out, M, 1024, 1024);
}

// Round 13
// 271.486 us; speedup vs baseline: 1.2145x; 1.0193x over previous
//
#include <hip/hip_runtime.h>
#include <stdint.h>

typedef unsigned short u16;
typedef unsigned int u32;
typedef __attribute__((ext_vector_type(8))) short bf16x8;
typedef __attribute__((ext_vector_type(4))) float f32x4;

__device__ __forceinline__ float bf2f(u16 u) {
    union { u32 i; float f; } v; v.i = ((u32)u) << 16; return v.f;
}
__device__ __forceinline__ u16 f2bf(float f) {
    union { float f; u32 i; } v; v.f = f;
    u32 x = v.i;
    u32 r = (x + 0x7FFFu + ((x >> 16) & 1u)) >> 16;  // RNE
    return (u16)r;
}

__device__ __forceinline__ void gld_lds16(const void* g, void* l) {
    __builtin_amdgcn_global_load_lds(
        (const __attribute__((address_space(1))) void*)g,
        (__attribute__((address_space(3))) void*)l, 16, 0, 0);
}

// ---------------- f32 -> bf16 row convert (vectorized) ---------------------
__global__ __launch_bounds__(256) void cvt_rows(
    const float* __restrict__ src, u16* __restrict__ dst, size_t total4) {
    size_t i = (size_t)blockIdx.x * 256 + threadIdx.x;  // one float4 per thread
    if (i >= total4) return;
    const float4 v = ((const float4*)src)[i];
    u16 o[4] = {f2bf(v.x), f2bf(v.y), f2bf(v.z), f2bf(v.w)};
    *(unsigned long long*)(dst + i * 4) = *(unsigned long long*)o;
}

// ---------------- transpose+convert: dst_bf16[c][r] = src_f32[r][c] --------
__global__ __launch_bounds__(256) void transpose_cvt(
    const float* __restrict__ src, u16* __restrict__ dst, int R, int C) {
    __shared__ float tile[32][33];
    int c0 = blockIdx.x * 32, r0 = blockIdx.y * 32;
    int tx = threadIdx.x & 31, ty = threadIdx.x >> 5;  // ty 0..7
    for (int rr = ty; rr < 32; rr += 8)
        tile[rr][tx] = src[(size_t)(r0 + rr) * C + c0 + tx];
    __syncthreads();
    for (int rr = ty; rr < 32; rr += 8)
        dst[(size_t)(c0 + rr) * R + r0 + tx] = f2bf(tile[tx][rr]);
}

// ---------------- GEMM v7 (r12 verified): 128x256 block, wave 64x128 -------
// C[M][N] = A[M][K] * Bt[N][K]^T. MODE 0: bf16 out. MODE 1: f32 out + bias.
// 3-deep LDS ring (72 KB -> 2 blocks/CU), depth-2 prefetch, counted vmcnt(6)
// mid-loop, vmcnt(0) only at last tile; single barrier per K-tile.
// Chunk swizzle (bank-conflict 0 measured): slot = chunk ^ ((row>>1)&3) via
// pre-swizzled global source (linear gld_lds dest, G21) + same XOR on read.
// Grid: blockIdx.x = n-tile (fastest) -> A m-panel L2 reuse.
template <int MODE>
__global__ __launch_bounds__(256, 2) void gemm_bt7(
    const u16* __restrict__ A, const u16* __restrict__ Bt,
    const float* __restrict__ bias, void* __restrict__ Cv,
    int M, int N, int K) {
    __shared__ u16 Asb[3][128 * 32];   // 24 KB
    __shared__ u16 Bsb[3][256 * 32];   // 48 KB
    int tid = threadIdx.x;
    int wid = tid >> 6, lane = tid & 63;
    int lr = lane & 15, lq = lane >> 4;
    int wr = wid >> 1, wc = wid & 1;          // 2m x 2n, wave = 64m x 128n
    int n0 = blockIdx.x * 256, m0 = blockIdx.y * 128;
    int NT = K >> 5;
    f32x4 acc[4][8] = {};

    #define ST_A(u, t, bi)                                                   \
    do {                                                                     \
        int g = (u) * 256 + tid;            /* 0..511 */                     \
        int row = g >> 2;                   /* 0..127 */                     \
        int c = (g & 3) ^ ((row >> 1) & 3);                                  \
        int gm = m0 + row; if (gm >= M) gm = M - 1;                          \
        gld_lds16(A + (size_t)gm * K + ((t) << 5) + c * 8,                   \
                  &Asb[bi][g * 8]);                                          \
    } while (0)
    #define ST_B(u, t, bi)                                                   \
    do {                                                                     \
        int g = (u) * 256 + tid;            /* 0..1023 */                    \
        int row = g >> 2;                   /* 0..255 */                     \
        int c = (g & 3) ^ ((row >> 1) & 3);                                  \
        gld_lds16(Bt + (size_t)(n0 + row) * K + ((t) << 5) + c * 8,          \
                  &Bsb[bi][g * 8]);                                          \
    } while (0)
    #define ST_TILE(t, bi)                                                   \
    do {                                                                     \
        ST_A(0, t, bi); ST_A(1, t, bi);                                      \
        ST_B(0, t, bi); ST_B(1, t, bi); ST_B(2, t, bi); ST_B(3, t, bi);      \
    } while (0)

    ST_TILE(0, 0);
    ST_TILE(1, 1);

    int bcur = 0;
    for (int t = 0; t < NT; ++t) {
        if (t + 1 < NT) asm volatile("s_waitcnt vmcnt(6)" ::: "memory");
        else            asm volatile("s_waitcnt vmcnt(0)" ::: "memory");
        asm volatile("s_barrier" ::: "memory");
        const u16* Ab = &Asb[bcur][0];
        const u16* Bb = &Bsb[bcur][0];
        bf16x8 a[4], b[8];
        #pragma unroll
        for (int mi = 0; mi < 4; ++mi) {
            int r = wr * 64 + mi * 16 + lr;
            int cs = lq ^ ((r >> 1) & 3);
            a[mi] = *(const bf16x8*)&Ab[r * 32 + cs * 8];
        }
        #pragma unroll
        for (int ni = 0; ni < 8; ++ni) {
            int r = wc * 128 + ni * 16 + lr;
            int cs = lq ^ ((r >> 1) & 3);
            b[ni] = *(const bf16x8*)&Bb[r * 32 + cs * 8];
        }
        if (t + 2 < NT) {
            int bst = bcur + 2; if (bst >= 3) bst -= 3;
            ST_TILE(t + 2, bst);
        }
        __builtin_amdgcn_s_setprio(1);
        #pragma unroll
        for (int mi = 0; mi < 4; ++mi)
            #pragma unroll
            for (int ni = 0; ni < 8; ++ni)
                acc[mi][ni] = __builtin_amdgcn_mfma_f32_16x16x32_bf16(
                    a[mi], b[ni], acc[mi][ni], 0, 0, 0);
        __builtin_amdgcn_s_setprio(0);
        bcur = bcur + 1; if (bcur == 3) bcur = 0;
    }
    #undef ST_A
    #undef ST_B
    #undef ST_TILE

    #pragma unroll
    for (int mi = 0; mi < 4; ++mi)
        #pragma unroll
        for (int ni = 0; ni < 8; ++ni) {
            int col = n0 + wc * 128 + ni * 16 + lr;
            float bv = (MODE == 1) ? bias[col] : 0.0f;
            #pragma unroll
            for (int r = 0; r < 4; ++r) {
                int row = m0 + wr * 64 + mi * 16 + lq * 4 + r;
                if (row < M) {
                    if (MODE == 0)
                        ((u16*)Cv)[(size_t)row * N + col] = f2bf(acc[mi][ni][r]);
                    else
                        ((float*)Cv)[(size_t)row * N + col] = acc[mi][ni][r] + bv;
                }
            }
        }
}

// ---------------- bos row: attn_out[b*4097][:] = v[b, n=0, :] --------------
__global__ __launch_bounds__(256) void bos_copy(
    const u16* __restrict__ qkv, u16* __restrict__ attn_out) {
    int b = blockIdx.x;
    int c = blockIdx.y * 256 + threadIdx.x;  // 0..1023
    attn_out[(size_t)b * 4097 * 1024 + c] =
        qkv[(size_t)b * 4097 * 3072 + 2048 + c];
}

// P-LDS swizzle: layout [j 0..63][i 0..15][h 0..15] bf16, byte = j*512+i*32+2h,
// XOR 3 bank-bits (byte 4..6) with a (j,i)-hash. b128-safe (bits >= 4), and
// h0..7 / h8..15 16B-blocks stay contiguous (hash independent of h).
__device__ __forceinline__ int pswz(int j, int i, int h) {
    int byte = j * 512 + i * 32 + h * 2;
    int sw = ((j & 7) ^ ((j >> 3) & 7) ^ ((i >> 2) & 3)) & 7;
    return byte ^ (sw << 4);
}

// ---------------- fused windowed attention + talking-heads -----------------
// one WG (8 waves, 512 thr) per (x, b) — the r13 re-partition: same
// algorithm as r11/r12 but each wave owns HALF the prior serial work
// (2 heads in phase 1, 8 mix j-tiles, 2 heads in phase 2). Attn is
// latency-chain bound (~7% MFMA util), so halving the chain at equal
// wave-occupancy (2 blocks/CU x 8 waves = 16 waves/CU) should ~halve time.
// q-token i of tile x: t = 1 + x*16 + i. window j=0 -> bos,
// j=1..48 -> t = 1 + (x*16 - 32 + (j-1)). mask j <= i+33 => j>=49 masked.
// Talking-heads mix: ONE MFMA pass in place in P (r11, verified).
__global__ __launch_bounds__(512) void attn_kernel(
    const u16* __restrict__ qkv, const float* __restrict__ w_th,
    u16* __restrict__ attn_out) {
    __shared__ u16 P[64 * 16 * 16];   // 32 KB, swizzled [j][i][h->g]
    __shared__ u16 vt[8][2048];       // 4 KB/wave: [4 dblk][32 j][16 d]

    int tid = threadIdx.x;
    int wid = tid >> 6, lane = tid & 63;   // wid 0..7
    int x = blockIdx.x;                        // 0..255
    int b = blockIdx.y;                        // 0..3
    size_t base = (size_t)b * 4097 * 3072;
    int lr = lane & 15;
    int lq = lane >> 4;
    int lk8 = lq * 8;

    // B-frag for the mix MFMA: row g = lr, k = h = lk8+e (zero for k >= 16).
    bf16x8 bwth = {};
    if (lq < 2) {
        #pragma unroll
        for (int e = 0; e < 8; ++e)
            bwth[e] = (short)f2bf(w_th[lr * 16 + lk8 + e]);
    }

    // ---- phase 1: per-head QK^T + mask + softmax -> P (2 heads/wave) -------
    for (int hh = 0; hh < 2; ++hh) {
        int h = wid * 2 + hh;
        const u16* qp = qkv + base + (size_t)(1 + x * 16 + lr) * 3072 + h * 64;
        bf16x8 aq0 = *(const bf16x8*)(qp + lk8);
        bf16x8 aq1 = *(const bf16x8*)(qp + 32 + lk8);
        f32x4 acc[4];
        #pragma unroll
        for (int jt = 0; jt < 4; ++jt) {
            int j = jt * 16 + lr;
            int tpos = x * 16 - 32 + (j - 1);
            int t = (j > 0 && tpos >= 0 && tpos < 4096) ? tpos + 1 : 0;
            const u16* kp = qkv + base + (size_t)t * 3072 + 1024 + h * 64;
            bf16x8 bk0 = *(const bf16x8*)(kp + lk8);
            bf16x8 bk1 = *(const bf16x8*)(kp + 32 + lk8);
            f32x4 c = {};
            c = __builtin_amdgcn_mfma_f32_16x16x32_bf16(aq0, bk0, c, 0, 0, 0);
            c = __builtin_amdgcn_mfma_f32_16x16x32_bf16(aq1, bk1, c, 0, 0, 0);
            acc[jt] = c;
        }
        // mask + softmax over j (16 lanes x 4 tiles hold the j axis)
        float m[4], s[4], p[4][4];
        #pragma unroll
        for (int r = 0; r < 4; ++r) m[r] = -3.0e38f;
        #pragma unroll
        for (int jt = 0; jt < 4; ++jt) {
            int j = jt * 16 + lr;
            int tpos = x * 16 - 32 + (j - 1);
            bool jvalid = (j == 0) || (tpos >= 0);
            #pragma unroll
            for (int r = 0; r < 4; ++r) {
                int i = lq * 4 + r;
                bool keep = jvalid && (j == 0 || j <= i + 33);
                float v = keep ? acc[jt][r] * 0.125f : -3.0e38f;
                p[jt][r] = v;
                m[r] = fmaxf(m[r], v);
            }
        }
        #pragma unroll
        for (int r = 0; r < 4; ++r) {
            float v = m[r];
            v = fmaxf(v, __shfl_xor(v, 1));
            v = fmaxf(v, __shfl_xor(v, 2));
            v = fmaxf(v, __shfl_xor(v, 4));
            v = fmaxf(v, __shfl_xor(v, 8));
            m[r] = v; s[r] = 0.0f;
        }
        #pragma unroll
        for (int jt = 0; jt < 4; ++jt)
            #pragma unroll
            for (int r = 0; r < 4; ++r) {
                float e = __expf(p[jt][r] - m[r]);
                p[jt][r] = e; s[r] += e;
            }
        #pragma unroll
        for (int r = 0; r < 4; ++r) {
            float v = s[r];
            v += __shfl_xor(v, 1); v += __shfl_xor(v, 2);
            v += __shfl_xor(v, 4); v += __shfl_xor(v, 8);
            s[r] = 1.0f / v;
        }
        #pragma unroll
        for (int jt = 0; jt < 4; ++jt) {
            int j = jt * 16 + lr;
            #pragma unroll
            for (int r = 0; r < 4; ++r) {
                int i = lq * 4 + r;
                *(u16*)((char*)P + pswz(j, i, h)) = f2bf(p[jt][r] * s[r]);
            }
        }
    }
    __syncthreads();

    // ---- mix: 8 MFMA per wave, in place in P (wave owns j in [wid*8,+8)) ---
    #pragma unroll
    for (int jj = 0; jj < 8; ++jj) {
        int j = wid * 8 + jj;
        bf16x8 a = {};
        if (lq < 2)
            a = *(const bf16x8*)((const char*)P + pswz(j, lr, lk8));
        f32x4 c = {};
        c = __builtin_amdgcn_mfma_f32_16x16x32_bf16(a, bwth, c, 0, 0, 0);
        #pragma unroll
        for (int r = 0; r < 4; ++r)
            *(u16*)((char*)P + pswz(j, lq * 4 + r, lr)) = f2bf(c[r]);
    }
    __syncthreads();

    // ---- phase 2: per-head PV MFMA, 2 heads/wave ----------------------------
    const u16* vtw = &vt[wid][0];
    int jloc = lane >> 1, dh = lane & 1;
    for (int gg = 0; gg < 2; ++gg) {
        int g = wid * 2 + gg;
        f32x4 oacc[4] = {};
        #pragma unroll
        for (int kk = 0; kk < 2; ++kk) {
            {
                int jg = kk * 32 + jloc;
                int tpos = x * 16 - 32 + (jg - 1);
                int t = (jg > 0 && tpos >= 0 && tpos < 4096) ? tpos + 1 : 0;
                const u16* src = qkv + base + (size_t)t * 3072 + 2048 + g * 64
                               + dh * 8;
                #pragma unroll
                for (int w = 0; w < 4; ++w)
                    gld_lds16(src + w * 16, &vt[wid][w * 512 + lane * 8]);
            }
            // A-frag: av[e] = mixed[(j = kk*32 + lk8 + e, i = lr)][g]
            bf16x8 av;
            #pragma unroll
            for (int e = 0; e < 8; ++e)
                av[e] = (short)*(const u16*)
                    ((const char*)P + pswz(kk * 32 + lk8 + e, lr, g));
            asm volatile("s_waitcnt vmcnt(0)" ::: "memory");
            // B-frags: scalar column gathers from row-major subtiles.
            #pragma unroll
            for (int dt = 0; dt < 4; ++dt) {
                bf16x8 bv;
                #pragma unroll
                for (int e = 0; e < 8; ++e)
                    bv[e] = (short)vtw[dt * 512 + (lk8 + e) * 16 + lr];
                oacc[dt] = __builtin_amdgcn_mfma_f32_16x16x32_bf16(
                    av, bv, oacc[dt], 0, 0, 0);
            }
        }
        #pragma unroll
        for (int dt = 0; dt < 4; ++dt) {
            int col = g * 64 + dt * 16 + lr;
            #pragma unroll
            for (int r = 0; r < 4; ++r) {
                int i = lq * 4 + r;
                size_t row = (size_t)b * 4097 + 1 + (size_t)x * 16 + i;
                attn_out[row * 1024 + col] = f2bf(oacc[dt][r]);
            }
        }
    }
}

// ---------------------------------------------------------------------------
extern "C" void kernel_launch(void* const* d_in, const int* in_sizes, int n_in,
                              void* d_out, int out_size, void* d_ws, size_t ws_size,
                              hipStream_t stream) {
    const float* x     = (const float*)d_in[0];  // (4,4097,1024) f32
    const float* w_qkv = (const float*)d_in[1];  // (1024,3072)  f32
    const float* w_out = (const float*)d_in[2];  // (1024,1024)  f32
    const float* b_out = (const float*)d_in[3];  // (1024,)      f32
    const float* w_th  = (const float*)d_in[4];  // (16,16)      f32
    float* out = (float*)d_out;                  // (4,4097,1024) f32

    const int M = 4 * 4097;  // 16388
    u16* qkv      = (u16*)d_ws;                       // M x 3072      bf16
    u16* wqkvT    = qkv + (size_t)M * 3072;           // 3072 x 1024   bf16
    u16* woutT    = wqkvT + (size_t)3072 * 1024;      // 1024 x 1024   bf16
    u16* xb       = woutT + (size_t)1024 * 1024;      // M x 1024      bf16
    u16* attn_out = xb;  // aliases xb: xb dead after GEMM1 (stream-ordered)

    transpose_cvt<<<dim3(96, 32), 256, 0, stream>>>(w_qkv, wqkvT, 1024, 3072);
    transpose_cvt<<<dim3(32, 32), 256, 0, stream>>>(w_out, woutT, 1024, 1024);

    size_t total4 = (size_t)M * 1024 / 4;  // 4,195,328 float4s
    cvt_rows<<<(int)((total4 + 255) / 256), 256, 0, stream>>>(x, xb, total4);

    int mt = (M + 127) / 128;  // 129
    gemm_bt7<0><<<dim3(3072 / 256, mt), 256, 0, stream>>>(
        xb, wqkvT, nullptr, qkv, M, 3072, 1024);

    bos_copy<<<dim3(4, 4), 256, 0, stream>>>(qkv, attn_out);
    attn_kernel<<<dim3(256, 4), 512, 0, stream>>>(qkv, w_th, attn_out);

    gemm_bt7<1><<<dim3(1024 / 256, mt), 256, 0, stream>>>(
        attn_out, woutT, b_out, out, M, 1024, 1024);
}